// Round 5
// baseline (1021.245 us; speedup 1.0000x reference)
//
#include <hip/hip_runtime.h>
#include <hip/hip_bf16.h>

typedef __attribute__((ext_vector_type(8))) short s8v;
typedef __attribute__((ext_vector_type(4))) float f4v;
typedef __attribute__((ext_vector_type(4))) unsigned int u4v;

#define BATCH 32
#define SEQ   2048
#define DIM   256
#define ORIGIN_OFF ((size_t)BATCH * SEQ * DIM)

// LDS layout (bytes), total 65,024 static:
//   A @ 0      : [64 rows][264 shorts] stride 528B   (x_bf16 -> Q_bf16 -> agg_bf16)
//   B @ 33792  : 29,696B union:
//     S-phase : sK  [64 q][136 shorts] stride 272B (17,408)
//     W-stage : sB  [128 n][72 shorts] stride 144B (18,432)
//     PV      : sP  [64 m][72 shorts] stride 144B @ +0 (9,216)
//               sXt [256 d][40 shorts] stride 80B @ +9216 (20,480)
//     epilog  : cg floats @ +24576 (1,024), cb float @ +25600
//   C @ 63488  : 1,536B: stat_max[0,512) stat_sum[512,1024)
//                wp[0,1024) -> wcS[0,256), Ls[256,768), Lq[768,1280)
#define OFF_A 0
#define OFF_B 33792
#define OFF_C 63488

__device__ __forceinline__ unsigned short f2bf(float f) {
  __hip_bfloat16 h = __float2bfloat16(f);   // round-to-nearest-even
  return *reinterpret_cast<unsigned short*>(&h);
}
__device__ __forceinline__ f4v mfma16(s8v a, s8v b, f4v c) {
  return __builtin_amdgcn_mfma_f32_16x16x32_bf16(a, b, c, 0, 0, 0);
}
__device__ __forceinline__ unsigned int pk2(float lo, float hi) {
  return (unsigned int)f2bf(lo) | ((unsigned int)f2bf(hi) << 16);
}

// acc[a][nt] += (bf16 A-tile in region A) @ W(f32, [256 k][256 n] row-major),
// staged transposed+converted through region B. n = wc*128 + nt*16 + col16.
__device__ __forceinline__ void gemm_x_w(
    const float* __restrict__ W, char* sA, char* sB,
    f4v (*acc)[8], int tid, int col16, int quad, int rw, int wc)
{
  for (int h2 = 0; h2 < 2; ++h2) {        // n-half of 128
    for (int kq = 0; kq < 4; ++kq) {      // k-quarter of 64
      __syncthreads();
      { // stage W^T tile: sB[n_local 128][k_local 64] bf16
        const int dk = tid >> 2;          // 0..63
        const int nc = (tid & 3) * 32;
        const float* src = W + (size_t)(kq * 64 + dk) * DIM + h2 * 128 + nc;
        #pragma unroll
        for (int i = 0; i < 4; ++i) {
          f4v v0 = *(const f4v*)(src + i * 8);
          f4v v1 = *(const f4v*)(src + i * 8 + 4);
          #pragma unroll
          for (int e = 0; e < 4; ++e) {
            *(unsigned short*)(sB + (nc + i * 8 + e) * 144 + dk * 2) = f2bf(v0[e]);
            *(unsigned short*)(sB + (nc + i * 8 + 4 + e) * 144 + dk * 2) = f2bf(v1[e]);
          }
        }
      }
      __syncthreads();
      if (wc == h2) {
        #pragma unroll
        for (int s2 = 0; s2 < 2; ++s2) {  // K=32 steps within quarter
          s8v afr[2];
          #pragma unroll
          for (int a = 0; a < 2; ++a) {
            const int row = rw + a * 16 + col16;
            const int o = kq * 8 + s2 * 4 + quad;
            afr[a] = *(const s8v*)(sA + row * 528 + o * 16);
          }
          #pragma unroll
          for (int nt = 0; nt < 8; ++nt) {
            const int nl = nt * 16 + col16;
            s8v bfr = *(const s8v*)(sB + nl * 144 + (s2 * 4 + quad) * 16);
            acc[0][nt] = mfma16(afr[0], bfr, acc[0][nt]);
            acc[1][nt] = mfma16(afr[1], bfr, acc[1][nt]);
          }
        }
      }
    }
  }
}

__global__ __launch_bounds__(256, 2)
void tfs_kernel(
    const float* __restrict__ x,
    const float* __restrict__ mlp_w,
    const float* __restrict__ mlp_b,
    const float* __restrict__ his_w,
    const float* __restrict__ his_b,
    const float* __restrict__ cur_w,
    const float* __restrict__ cur_b,
    const float* __restrict__ wl_w,
    const float* __restrict__ wl_b,
    const float* __restrict__ gate_w,
    const float* __restrict__ gate_b,
    const float* __restrict__ ln_g,
    const float* __restrict__ ln_b,
    float* __restrict__ out)
{
  __shared__ __align__(16) char smem[65024];
  char* sA = smem + OFF_A;
  char* sB = smem + OFF_B;
  char* sC = smem + OFF_C;

  const int tid = threadIdx.x;
  const int lane = tid & 63;
  const int w = tid >> 6;
  const int col16 = lane & 15;
  const int quad = lane >> 4;
  const int wr = w & 1, wc = w >> 1;
  const int rw = wr * 32;
  const int b = blockIdx.y;
  const int p0 = blockIdx.x * 64;
  const float* xb = x + (size_t)b * SEQ * DIM;
  const f4v zero4 = {0.f, 0.f, 0.f, 0.f};

  // ---- stage x p-rows into A as bf16 ----
  {
    const int row = tid >> 2, cs = (tid & 3) * 64;
    const float* src = xb + (size_t)(p0 + row) * DIM + cs;
    char* dst = sA + row * 528 + cs * 2;
    #pragma unroll
    for (int j = 0; j < 8; ++j) {
      f4v a = *(const f4v*)(src + j * 8);
      f4v c = *(const f4v*)(src + j * 8 + 4);
      u4v o;
      o[0] = pk2(a[0], a[1]); o[1] = pk2(a[2], a[3]);
      o[2] = pk2(c[0], c[1]); o[3] = pk2(c[2], c[3]);
      *(u4v*)(dst + j * 16) = o;
    }
  }

  // ---- Q = x @ his_w + his_b (regs -> in-place bf16 into A) ----
  {
    f4v accQ[2][8];
    #pragma unroll
    for (int a = 0; a < 2; ++a)
      #pragma unroll
      for (int nt = 0; nt < 8; ++nt) accQ[a][nt] = zero4;
    gemm_x_w(his_w, sA, sB, accQ, tid, col16, quad, rw, wc);
    __syncthreads();   // all x reads done -> safe to overwrite A
    #pragma unroll
    for (int a = 0; a < 2; ++a)
      #pragma unroll
      for (int nt = 0; nt < 8; ++nt) {
        const int n = wc * 128 + nt * 16 + col16;
        const float bias = his_b[n];
        #pragma unroll
        for (int r = 0; r < 4; ++r) {
          const int row = rw + a * 16 + quad * 4 + r;
          *(unsigned short*)(sA + row * 528 + n * 2) = f2bf(accQ[a][nt][r] + bias);
        }
      }
  }

  // ---- flash loop ----
  f4v accO[2][8];
  #pragma unroll
  for (int a = 0; a < 2; ++a)
    #pragma unroll
    for (int dt = 0; dt < 8; ++dt) accO[a][dt] = zero4;
  float mrun[2][4], Zrun[2][4];
  #pragma unroll
  for (int a = 0; a < 2; ++a)
    #pragma unroll
    for (int r = 0; r < 4; ++r) { mrun[a][r] = -1.0e30f; Zrun[a][r] = 0.f; }

  float* stat_max = (float*)(sC);        // [2][64]
  float* stat_sum = (float*)(sC + 512);  // [2][64]

  for (int qi = 0; qi < 32; ++qi) {
    const int q0 = qi * 64;
    const bool active = (q0 <= p0);
    f4v accS[2][2];
    accS[0][0] = zero4; accS[0][1] = zero4; accS[1][0] = zero4; accS[1][1] = zero4;

    // S = Q @ wl_w[:, q0:q0+64], two k-halves of 128
    for (int h = 0; h < 2; ++h) {
      __syncthreads();                   // region B reuse
      { // stage sK[q 64][k_local 128] transposed+converted from wl_w
        const int dk = tid >> 1;         // 0..127
        const int qc = (tid & 1) * 32;
        const float* src = wl_w + (size_t)(h * 128 + dk) * SEQ + q0 + qc;
        #pragma unroll
        for (int i = 0; i < 4; ++i) {
          f4v v0 = *(const f4v*)(src + i * 8);
          f4v v1 = *(const f4v*)(src + i * 8 + 4);
          #pragma unroll
          for (int e = 0; e < 4; ++e) {
            *(unsigned short*)(sB + (qc + i * 8 + e) * 272 + dk * 2) = f2bf(v0[e]);
            *(unsigned short*)(sB + (qc + i * 8 + 4 + e) * 272 + dk * 2) = f2bf(v1[e]);
          }
        }
      }
      __syncthreads();
      #pragma unroll
      for (int s = 0; s < 4; ++s) {
        s8v afr[2];
        #pragma unroll
        for (int a = 0; a < 2; ++a) {
          const int row = rw + a * 16 + col16;
          const int o = h * 16 + s * 4 + quad;
          afr[a] = *(const s8v*)(sA + row * 528 + o * 16);
        }
        #pragma unroll
        for (int t = 0; t < 2; ++t) {
          const int ql = wc * 32 + t * 16 + col16;
          s8v bfr = *(const s8v*)(sB + ql * 272 + (s * 4 + quad) * 16);
          accS[0][t] = mfma16(afr[0], bfr, accS[0][t]);
          accS[1][t] = mfma16(afr[1], bfr, accS[1][t]);
        }
      }
    }

    // + wl_b
    #pragma unroll
    for (int t = 0; t < 2; ++t) {
      const float wlb = wl_b[q0 + wc * 32 + t * 16 + col16];
      #pragma unroll
      for (int a = 0; a < 2; ++a)
        #pragma unroll
        for (int r = 0; r < 4; ++r) accS[a][t][r] += wlb;
    }

    // row max
    float mx[2][4];
    #pragma unroll
    for (int a = 0; a < 2; ++a)
      #pragma unroll
      for (int r = 0; r < 4; ++r) {
        float v = fmaxf(accS[a][0][r], accS[a][1][r]);
        v = fmaxf(v, __shfl_xor(v, 1, 64));
        v = fmaxf(v, __shfl_xor(v, 2, 64));
        v = fmaxf(v, __shfl_xor(v, 4, 64));
        v = fmaxf(v, __shfl_xor(v, 8, 64));
        mx[a][r] = v;
      }
    if (col16 == 0) {
      #pragma unroll
      for (int a = 0; a < 2; ++a)
        #pragma unroll
        for (int r = 0; r < 4; ++r)
          stat_max[wc * 64 + rw + a * 16 + quad * 4 + r] = mx[a][r];
    }
    __syncthreads();                     // [B1] sK reads drained too

    float alpha[2][4];
    #pragma unroll
    for (int a = 0; a < 2; ++a)
      #pragma unroll
      for (int r = 0; r < 4; ++r) {
        const int row = rw + a * 16 + quad * 4 + r;
        const float mt = fmaxf(stat_max[row], stat_max[64 + row]);
        const float mn = fmaxf(mrun[a][r], mt);
        alpha[a][r] = __expf(fminf(mrun[a][r] - mn, 0.f));
        mrun[a][r] = mn;
      }

    float Pv[2][2][4];
    #pragma unroll
    for (int a = 0; a < 2; ++a)
      #pragma unroll
      for (int t = 0; t < 2; ++t)
        #pragma unroll
        for (int r = 0; r < 4; ++r)
          Pv[a][t][r] = __expf(fminf(accS[a][t][r] - mrun[a][r], 0.f));

    // row sums (unmasked denominator over all q)
    float ps[2][4];
    #pragma unroll
    for (int a = 0; a < 2; ++a)
      #pragma unroll
      for (int r = 0; r < 4; ++r) {
        float v = Pv[a][0][r] + Pv[a][1][r];
        v += __shfl_xor(v, 1, 64);
        v += __shfl_xor(v, 2, 64);
        v += __shfl_xor(v, 4, 64);
        v += __shfl_xor(v, 8, 64);
        ps[a][r] = v;
      }
    if (col16 == 0) {
      #pragma unroll
      for (int a = 0; a < 2; ++a)
        #pragma unroll
        for (int r = 0; r < 4; ++r)
          stat_sum[wc * 64 + rw + a * 16 + quad * 4 + r] = ps[a][r];
    }

    if (active) { // masked P (tril, q<=p) -> sP bf16 (safe after B1)
      #pragma unroll
      for (int a = 0; a < 2; ++a)
        #pragma unroll
        for (int t = 0; t < 2; ++t)
          #pragma unroll
          for (int r = 0; r < 4; ++r) {
            const int row = rw + a * 16 + quad * 4 + r;
            const int ql = wc * 32 + t * 16 + col16;
            const float pv = ((q0 + ql) <= (p0 + row)) ? Pv[a][t][r] : 0.f;
            *(unsigned short*)(sB + row * 144 + ql * 2) = f2bf(pv);
          }
    }
    __syncthreads();                     // [B2] stats + sP visible

    #pragma unroll
    for (int a = 0; a < 2; ++a)
      #pragma unroll
      for (int r = 0; r < 4; ++r) {
        const int row = rw + a * 16 + quad * 4 + r;
        const float st = stat_sum[row] + stat_sum[64 + row];
        Zrun[a][r] = Zrun[a][r] * alpha[a][r] + st;
      }
    #pragma unroll
    for (int a = 0; a < 2; ++a)
      #pragma unroll
      for (int dt = 0; dt < 8; ++dt)
        #pragma unroll
        for (int r = 0; r < 4; ++r) accO[a][dt][r] *= alpha[a][r];

    if (active) {
      for (int h = 0; h < 2; ++h) {
        __syncthreads();                 // protect sXt region
        { // stage sXt[d 256][qloc 32] transposed+converted from x rows
          const int qrow = tid >> 3;     // 0..31
          const int dc = (tid & 7) * 32;
          const float* src = xb + (size_t)(q0 + h * 32 + qrow) * DIM + dc;
          #pragma unroll
          for (int i = 0; i < 4; ++i) {
            f4v v0 = *(const f4v*)(src + i * 8);
            f4v v1 = *(const f4v*)(src + i * 8 + 4);
            #pragma unroll
            for (int e = 0; e < 4; ++e) {
              *(unsigned short*)(sB + 9216 + (dc + i * 8 + e) * 80 + qrow * 2) = f2bf(v0[e]);
              *(unsigned short*)(sB + 9216 + (dc + i * 8 + 4 + e) * 80 + qrow * 2) = f2bf(v1[e]);
            }
          }
        }
        __syncthreads();
        s8v ap[2];
        #pragma unroll
        for (int a = 0; a < 2; ++a) {
          const int row = rw + a * 16 + col16;
          ap[a] = *(const s8v*)(sB + row * 144 + (h * 4 + quad) * 16);
        }
        #pragma unroll
        for (int dt = 0; dt < 8; ++dt) {
          const int d = wc * 128 + dt * 16 + col16;
          s8v bv = *(const s8v*)(sB + 9216 + d * 80 + quad * 16);
          accO[0][dt] = mfma16(ap[0], bv, accO[0][dt]);
          accO[1][dt] = mfma16(ap[1], bv, accO[1][dt]);
        }
      }
    }
  } // qi

  // ---- epilogue: agg = O/Z -> A (bf16) ----
  __syncthreads();
  #pragma unroll
  for (int a = 0; a < 2; ++a)
    #pragma unroll
    for (int dt = 0; dt < 8; ++dt) {
      const int n = wc * 128 + dt * 16 + col16;
      #pragma unroll
      for (int r = 0; r < 4; ++r) {
        const int row = rw + a * 16 + quad * 4 + r;
        const float invZ = 1.0f / fmaxf(Zrun[a][r], 1e-30f);
        *(unsigned short*)(sA + row * 528 + n * 2) = f2bf(accO[a][dt][r] * invZ);
      }
    }

  // ---- H_hist = agg @ mlp_w ----
  f4v accH[2][8];
  #pragma unroll
  for (int a = 0; a < 2; ++a)
    #pragma unroll
    for (int nt = 0; nt < 8; ++nt) accH[a][nt] = zero4;
  gemm_x_w(mlp_w, sA, sB, accH, tid, col16, quad, rw, wc);
  __syncthreads();

  // ---- cg[d] = cur_w[d,:]·gate_w ; cb ----
  float* cgL = (float*)(sB + 24576);
  float* cbL = (float*)(sB + 25600);
  {
    const float* cw = cur_w + (size_t)tid * DIM;
    float s = 0.f;
    #pragma unroll 8
    for (int i = 0; i < 64; ++i) {
      f4v vc = *(const f4v*)(cw + i * 4);
      f4v vg = *(const f4v*)(gate_w + i * 4);
      s += vc[0] * vg[0] + vc[1] * vg[1] + vc[2] * vg[2] + vc[3] * vg[3];
    }
    cgL[tid] = s;
    if (tid == 0) {
      float s2 = 0.f;
      for (int j = 0; j < DIM; ++j) s2 += cur_b[j] * gate_w[j];
      cbL[0] = s2 + gate_b[0];
    }
  }
  __syncthreads();

  // ---- wc[p] = x[p]·cg + cb (x from global, fp32) ----
  float* wp = (float*)sC;          // [64][4]
  {
    const int row = tid & 63, sg = tid >> 6;
    const float* xr = xb + (size_t)(p0 + row) * DIM + sg * 64;
    const float* cgp = cgL + sg * 64;
    float sacc = 0.f;
    #pragma unroll
    for (int i = 0; i < 16; ++i) {
      f4v xv4 = *(const f4v*)(xr + i * 4);
      sacc += xv4[0] * cgp[i * 4] + xv4[1] * cgp[i * 4 + 1]
            + xv4[2] * cgp[i * 4 + 2] + xv4[3] * cgp[i * 4 + 3];
    }
    wp[row * 4 + sg] = sacc;
  }
  __syncthreads();
  float* wcS = (float*)sC;         // [64], wave-0 own-slot overwrite
  if (tid < 64) {
    const float v = wp[tid * 4] + wp[tid * 4 + 1] + wp[tid * 4 + 2] + wp[tid * 4 + 3] + cbL[0];
    wcS[tid] = v;
  }
  __syncthreads();

  // ---- h = H_hist + mlp_b + wc*x ; LN ----
  float s1l[2][4], s2l[2][4];
  #pragma unroll
  for (int a = 0; a < 2; ++a)
    #pragma unroll
    for (int r = 0; r < 4; ++r) { s1l[a][r] = 0.f; s2l[a][r] = 0.f; }
  #pragma unroll
  for (int a = 0; a < 2; ++a)
    #pragma unroll
    for (int nt = 0; nt < 8; ++nt) {
      const int n = wc * 128 + nt * 16 + col16;
      const float mb = mlp_b[n];
      #pragma unroll
      for (int r = 0; r < 4; ++r) {
        const int row = rw + a * 16 + quad * 4 + r;
        const float xv = xb[(size_t)(p0 + row) * DIM + n];
        const float v = accH[a][nt][r] + mb + wcS[row] * xv;
        accH[a][nt][r] = v;
        s1l[a][r] += v;
        s2l[a][r] += v * v;
      }
    }
  #pragma unroll
  for (int a = 0; a < 2; ++a)
    #pragma unroll
    for (int r = 0; r < 4; ++r) {
      float v1 = s1l[a][r], v2 = s2l[a][r];
      v1 += __shfl_xor(v1, 1, 64); v2 += __shfl_xor(v2, 1, 64);
      v1 += __shfl_xor(v1, 2, 64); v2 += __shfl_xor(v2, 2, 64);
      v1 += __shfl_xor(v1, 4, 64); v2 += __shfl_xor(v2, 4, 64);
      v1 += __shfl_xor(v1, 8, 64); v2 += __shfl_xor(v2, 8, 64);
      s1l[a][r] = v1; s2l[a][r] = v2;
    }
  float* Ls = (float*)(sC + 256);  // [2][64]
  float* Lq = (float*)(sC + 768);  // [2][64]
  if (col16 == 0) {
    #pragma unroll
    for (int a = 0; a < 2; ++a)
      #pragma unroll
      for (int r = 0; r < 4; ++r) {
        const int row = rw + a * 16 + quad * 4 + r;
        Ls[wc * 64 + row] = s1l[a][r];
        Lq[wc * 64 + row] = s2l[a][r];
      }
  }
  __syncthreads();

  #pragma unroll
  for (int a = 0; a < 2; ++a) {
    float mean_[4], rstd_[4];
    #pragma unroll
    for (int r = 0; r < 4; ++r) {
      const int row = rw + a * 16 + quad * 4 + r;
      const float S1 = Ls[row] + Ls[64 + row];
      const float S2 = Lq[row] + Lq[64 + row];
      const float mean = S1 * (1.0f / 256.0f);
      const float var = S2 * (1.0f / 256.0f) - mean * mean;
      mean_[r] = mean;
      rstd_[r] = rsqrtf(fmaxf(var, 0.f) + 1e-5f);
    }
    #pragma unroll
    for (int nt = 0; nt < 8; ++nt) {
      const int n = wc * 128 + nt * 16 + col16;
      const float g = ln_g[n];
      const float be = ln_b[n];
      #pragma unroll
      for (int r = 0; r < 4; ++r) {
        const int row = rw + a * 16 + quad * 4 + r;
        const float y = (accH[a][nt][r] - mean_[r]) * rstd_[r] * g + be;
        out[((size_t)b * SEQ + p0 + row) * DIM + n] = y;
      }
    }
  }

  // ---- origin passthrough: direct fp32 global->global ----
  {
    const int row = tid >> 2, cs = (tid & 3) * 64;
    const float* src = xb + (size_t)(p0 + row) * DIM + cs;
    float* dst = out + ORIGIN_OFF + ((size_t)b * SEQ + p0 + row) * DIM + cs;
    #pragma unroll
    for (int j = 0; j < 16; ++j)
      *(f4v*)(dst + j * 4) = *(const f4v*)(src + j * 4);
  }
}

extern "C" void kernel_launch(void* const* d_in, const int* in_sizes, int n_in,
                              void* d_out, int out_size, void* d_ws, size_t ws_size,
                              hipStream_t stream) {
  const float* x      = (const float*)d_in[0];
  const float* mlp_w  = (const float*)d_in[1];
  const float* mlp_b  = (const float*)d_in[2];
  const float* his_w  = (const float*)d_in[3];
  const float* his_b  = (const float*)d_in[4];
  const float* cur_w  = (const float*)d_in[5];
  const float* cur_b  = (const float*)d_in[6];
  const float* wl_w   = (const float*)d_in[7];
  const float* wl_b   = (const float*)d_in[8];
  const float* gate_w = (const float*)d_in[9];
  const float* gate_b = (const float*)d_in[10];
  const float* ln_g   = (const float*)d_in[11];
  const float* ln_b   = (const float*)d_in[12];

  tfs_kernel<<<dim3(32, 32), 256, 0, stream>>>(
      x, mlp_w, mlp_b, his_w, his_b, cur_w, cur_b, wl_w, wl_b,
      gate_w, gate_b, ln_g, ln_b, (float*)d_out);
}